// Round 4
// baseline (277.881 us; speedup 1.0000x reference)
//
#include <hip/hip_runtime.h>
#include <math.h>

// B=2048 rows, L=16384, W=30 sliding mean of sigmoid(x)*mask, per-row max.
constexpr int Bn    = 2048;
constexpr int L     = 16384;
constexpr int W     = 30;
constexpr int NT    = 256;
constexpr int TILE  = 2048;             // window starts per block
constexpr int TPB   = L / TILE;         // 8 blocks per row
constexpr int NELEM = TILE + W - 1;     // 2077 staged elements
constexpr int SPT   = TILE / NT;        // 8 window starts per thread
constexpr int KLD   = TILE / (4 * NT);  // 2 float4 DMA ops per thread per array
constexpr int PPAD  = NELEM + (NELEM >> 3) + 2;   // 2338 floats (pad +1 per 8)

typedef float f32x4 __attribute__((ext_vector_type(4)));

// HBM -> LDS direct DMA, 16B/lane, linear dest (wave-uniform base + lane*16).
#define GLDS(gsrc, ldst)                                                      \
    __builtin_amdgcn_global_load_lds(                                         \
        (const __attribute__((address_space(1))) void*)(gsrc),                \
        (__attribute__((address_space(3))) void*)(ldst), 16, 0, 0)

// LDS pad +1 float per 8 for prob. Window base for lane t: pidx(8t) = 9t ->
// odd multiplier -> 32 distinct bank residues per 32-lane phase: conflict-free.
// Offsets pidx(8t+c) - 9t = c + (c>>3): compile-time immediates.
__device__ __forceinline__ int pidx(int j) { return j + (j >> 3); }

__device__ __forceinline__ float sigp(float xv, float mv) {
    // m * 1/(1 + 2^(-x*log2(e))) : v_mul, v_exp, v_add, v_rcp, v_mul
    float t = -1.44269504089f * xv;
    float e;
    asm("v_exp_f32 %0, %1" : "=v"(e) : "v"(t));
    return mv * __builtin_amdgcn_rcpf(1.0f + e);
}

__global__ __launch_bounds__(NT)
void winmax_tile(const float* __restrict__ x,
                 const float* __restrict__ m,
                 float* __restrict__ out) {
    // Raw staging MUST be linear (global_load_lds writes base + lane*16; a
    // padded dest breaks the mapping, m104/m173). prob is padded separately.
    __shared__ float rawx[TILE];                       //  8 KiB
    __shared__ float rawm[TILE];                       //  8 KiB
    __shared__ float prob[PPAD];                       //  9.1 KiB  => ~25.7 KiB total, 6 blk/CU

    const int b    = blockIdx.x;
    const int row  = b >> 3;            // TPB = 8
    const int tile = b & 7;
    const int t    = threadIdx.x;
    const int ts   = tile * TILE;

    const float* xr = x + (size_t)row * L + ts;
    const float* mr = m + (size_t)row * L + ts;
    const f32x4* x4 = (const f32x4*)xr;
    const f32x4* m4 = (const f32x4*)mr;

    // ---- Halo first: W-1=29 elements past the tile via plain loads (tiny,
    // avoids OOB DMA on the final tile). Zero-fill: truncated-window sums are
    // subsets of the valid window at L-W (all terms >= 0) -> can't win the max.
    float xh = 0.0f, mh = 0.0f;
    if (t < W - 1 && ts + TILE + t < L) {
        xh = xr[TILE + t];
        mh = mr[TILE + t];
    }

    // ---- Stage raw tiles via HBM->LDS DMA. No destination VGPRs => nothing
    // for the compiler to serialize (rounds 0-1: VGPR_Count 20-24 proved it
    // kept ~1 dwordx4 outstanding -> 2.8 TB/s MLP ceiling). All 4 DMA ops per
    // wave stay in flight on vmcnt until the barrier: ~96 KB/CU in flight.
    const int wb = t & ~63;             // wave-uniform base thread of this wave
    #pragma unroll
    for (int k = 0; k < KLD; ++k)
        GLDS(x4 + (k * NT + t), rawx + (size_t)(k * NT + wb) * 4);
    #pragma unroll
    for (int k = 0; k < KLD; ++k)
        GLDS(m4 + (k * NT + t), rawm + (size_t)(k * NT + wb) * 4);
    __syncthreads();                    // drains vmcnt + lgkm before reads

    // ---- sigmoid(x)*mask from raw LDS into padded prob ----
    const f32x4* rx4 = (const f32x4*)rawx;
    const f32x4* rm4 = (const f32x4*)rawm;
    #pragma unroll
    for (int k = 0; k < KLD; ++k) {
        const f32x4 xv = rx4[k * NT + t];       // ds_read_b128, conflict-free
        const f32x4 mv = rm4[k * NT + t];
        const int j = (k * NT + t) * 4;
        const int p = pidx(j);                  // j%4==0 -> 4 contiguous floats
        prob[p + 0] = sigp(xv[0], mv[0]);
        prob[p + 1] = sigp(xv[1], mv[1]);
        prob[p + 2] = sigp(xv[2], mv[2]);
        prob[p + 3] = sigp(xv[3], mv[3]);
    }
    if (t < W - 1)
        prob[pidx(TILE + t)] = sigp(xh, mh);    // OOB lanes: mh=0 -> 0
    __syncthreads();

    // ---- Sliding windows: thread t owns starts [8t, 8t+7], branch-free ----
    const int base = 9 * t;             // = pidx(8t); odd stride -> no conflicts
    float keep[SPT - 1];
    float sum = 0.0f;
    #pragma unroll
    for (int c = 0; c < W; ++c) {       // offsets compile-time: c + (c>>3)
        const float v = prob[base + c + (c >> 3)];
        if (c < SPT - 1) keep[c] = v;
        sum += v;
    }
    float best = sum;
    #pragma unroll
    for (int i = 1; i < SPT; ++i) {
        const int c = W - 1 + i;
        sum += prob[base + c + (c >> 3)] - keep[i - 1];
        best = fmaxf(best, sum);
    }
    best *= (1.0f / W);

    // ---- Wave max-reduce, one atomic per wave (win_mean >= 0 -> uint order) ----
    #pragma unroll
    for (int off = 32; off > 0; off >>= 1)
        best = fmaxf(best, __shfl_down(best, off, 64));
    if ((t & 63) == 0)
        atomicMax((unsigned int*)(out + row), __float_as_uint(best));
}

extern "C" void kernel_launch(void* const* d_in, const int* in_sizes, int n_in,
                              void* d_out, int out_size, void* d_ws, size_t ws_size,
                              hipStream_t stream) {
    const float* x = (const float*)d_in[0];
    const float* m = (const float*)d_in[1];
    float* out = (float*)d_out;
    // out is poisoned 0xAA (negative float as bits) -> must zero for atomicMax.
    hipMemsetAsync(out, 0, Bn * sizeof(float), stream);
    winmax_tile<<<Bn * TPB, NT, 0, stream>>>(x, m, out);
}